// Round 9
// baseline (259.454 us; speedup 1.0000x reference)
//
#include <hip/hip_runtime.h>
#include <hip/hip_fp16.h>
#include <math.h>

#define N_NODES 100000
#define E_EDGES 1600000
#define IN_DIM  128
#define FEAT    64
#define OUT_DIM 64
#define NBKT    391            // ceil(100000/256) buckets of 256 nodes (dst>>8)
#define CAP     6144           // per-bucket capacity (avg 4096, >30 sigma slack)
#define RNG     4096           // edges per binscatter block
#define NSCB    ((E_EDGES + RNG - 1) / RNG)   // 391
#define G1B2    ((N_NODES + 127) / 128)       // 782: gemm1 row-blocks of 128
#define HTS     130                           // hT stride (2-way bank alias on staging = free)

typedef float vfloat2 __attribute__((ext_vector_type(2)));

// ---------------- binscatter: block-local counting sort into 391 dst-buckets ----------------
__global__ __launch_bounds__(256) void k_binscatter(
    const int* __restrict__ src, const int* __restrict__ dst,
    int* __restrict__ bucket_cursor, int* __restrict__ binned)
{
    __shared__ int hist[NBKT];
    __shared__ int baseS[NBKT];
    __shared__ int cursor[NBKT];
    __shared__ int gbase[NBKT];          // after reserve: gbase[b] - baseS[b]
    __shared__ int sA[512], sB[512];
    __shared__ int buf[RNG];             // 16 KB
    __shared__ unsigned short bkt[RNG];  // 8 KB

    const int tid  = threadIdx.x;
    const int e0   = blockIdx.x * RNG;
    const int ecnt = min(RNG, E_EDGES - e0);

    for (int i = tid; i < NBKT; i += 256) hist[i] = 0;
    __syncthreads();

    int dsave[16];
#pragma unroll
    for (int k = 0; k < 16; ++k) {
        int e = e0 + k * 256 + tid;
        int d = (e < E_EDGES) ? dst[e] : -1;
        dsave[k] = d;
        if (d >= 0) atomicAdd(&hist[d >> 8], 1);
    }
    __syncthreads();

    for (int i = tid; i < 512; i += 256) sA[i] = (i < NBKT) ? hist[i] : 0;
    __syncthreads();
    int* pa = sA; int* pb = sB;
    for (int off = 1; off < 512; off <<= 1) {
        for (int i = tid; i < 512; i += 256)
            pb[i] = pa[i] + ((i >= off) ? pa[i - off] : 0);
        __syncthreads();
        int* t = pa; pa = pb; pb = t;
    }
    for (int i = tid; i < NBKT; i += 256) {
        int ex = pa[i] - hist[i];
        baseS[i]  = ex;
        cursor[i] = ex;
    }
    __syncthreads();

#pragma unroll
    for (int k = 0; k < 16; ++k) {
        int d = dsave[k];
        if (d >= 0) {
            int e   = e0 + k * 256 + tid;
            int s   = src[e];
            int b   = d >> 8;
            int pos = atomicAdd(&cursor[b], 1);
            buf[pos] = ((d & 255) << 17) | s;   // dl:8b | src:17b
            bkt[pos] = (unsigned short)b;
        }
    }
    __syncthreads();

    for (int t = tid; t < NBKT; t += 256) {
        int cnt = hist[t];
        int g   = cnt ? atomicAdd(&bucket_cursor[t], cnt) : 0;
        gbase[t] = g - baseS[t];
    }
    __syncthreads();

    for (int i = tid; i < ecnt; i += 256) {
        int b   = bkt[i];
        int off = gbase[b] + i;
        if (off < CAP) binned[b * CAP + off] = buf[i];
    }
}

// ---------------- bucketfinal: inline scan + per-bucket node sort ----------------
__global__ __launch_bounds__(256) void k_bucketfinal(
    const int* __restrict__ binned, const int* __restrict__ bucket_cursor,
    int* __restrict__ deg, int* __restrict__ rowptr, int* __restrict__ src_sorted)
{
    __shared__ int sA[512], sB[512];
    __shared__ int hist[256];
    __shared__ int scn[256];
    __shared__ int cur[256];
    const int b   = blockIdx.x;
    const int tid = threadIdx.x;

    for (int i = tid; i < 512; i += 256) sA[i] = (i < NBKT) ? bucket_cursor[i] : 0;
    __syncthreads();
    int* pa = sA; int* pb = sB;
    for (int off = 1; off < 512; off <<= 1) {
        for (int i = tid; i < 512; i += 256)
            pb[i] = pa[i] + ((i >= off) ? pa[i - off] : 0);
        __syncthreads();
        int* t = pa; pa = pb; pb = t;
    }
    const int cnt  = bucket_cursor[b];
    const int eb   = pa[b] - cnt;
    const int base = b * CAP;
    __syncthreads();

    hist[tid] = 0;
    __syncthreads();
    for (int i = tid; i < cnt; i += 256)
        atomicAdd(&hist[binned[base + i] >> 17], 1);
    __syncthreads();

    int v = hist[tid];
    scn[tid] = v;
    __syncthreads();
    for (int off = 1; off < 256; off <<= 1) {
        int add = (tid >= off) ? scn[tid - off] : 0;
        __syncthreads();
        scn[tid] += add;
        __syncthreads();
    }
    int ex = scn[tid] - v;
    cur[tid] = ex;
    int n = b * 256 + tid;
    if (n < N_NODES) {
        deg[n]    = v;
        rowptr[n] = eb + ex;
    }
    if (b == 0 && tid == 0) rowptr[N_NODES] = E_EDGES;
    __syncthreads();

    for (int i = tid; i < cnt; i += 256) {
        int p   = binned[base + i];
        int dl  = p >> 17;
        int pos = atomicAdd(&cur[dl], 1);
        src_sorted[eb + pos] = p & 0x1FFFF;
    }
}

// ---------------- gemm1: 128-row blocks (grid 782) for occupancy; 2 rows/thread ----------------
__global__ __launch_bounds__(256, 3) void k_gemm1(
    const float* __restrict__ h, const float* __restrict__ W1,
    const float* __restrict__ b1, const int* __restrict__ deg,
    const float* __restrict__ gate_W,
    __half* __restrict__ xs2h, unsigned int* __restrict__ xq,
    float* __restrict__ aproj, float* __restrict__ bproj)
{
    __shared__ float Ws[IN_DIM * FEAT];   // 32 KB
    __shared__ float hT[16 * HTS];        // 8.1 KB transposed tile (128 rows x 16 k)
    const int tid = threadIdx.x;
    const int r0  = blockIdx.x * 128;

    for (int i = tid; i < IN_DIM * FEAT / 4; i += 256)
        ((float4*)Ws)[i] = ((const float4*)W1)[i];

    const int rg = tid >> 2;     // 0..63: row group (2 rows)
    const int cg = tid & 3;      // 0..3: col group == head
    const int c0 = cg * 16;
    float acc[2][16];
#pragma unroll
    for (int i = 0; i < 2; ++i)
#pragma unroll
        for (int j = 0; j < 16; ++j) acc[i][j] = 0.f;

    for (int kc = 0; kc < IN_DIM / 16; ++kc) {
        // stage 128 rows x 16 k, transposed: 512 float4, 2 per thread
        float4 f[2];
#pragma unroll
        for (int it = 0; it < 2; ++it) {
            int idx = tid + it * 256;
            int row = idx >> 2;          // 0..127
            int q   = idx & 3;           // k-quad
            int gr  = r0 + row;
            f[it] = (gr < N_NODES)
                ? *(const float4*)(h + (size_t)gr * IN_DIM + kc * 16 + q * 4)
                : make_float4(0.f, 0.f, 0.f, 0.f);
        }
        __syncthreads();
#pragma unroll
        for (int it = 0; it < 2; ++it) {
            int idx = tid + it * 256;
            int row = idx >> 2;
            int q   = idx & 3;
            hT[(q * 4 + 0) * HTS + row] = f[it].x;
            hT[(q * 4 + 1) * HTS + row] = f[it].y;
            hT[(q * 4 + 2) * HTS + row] = f[it].z;
            hT[(q * 4 + 3) * HTS + row] = f[it].w;
        }
        __syncthreads();
#pragma unroll
        for (int kk = 0; kk < 16; ++kk) {
            float2 a2 = *(const float2*)&hT[kk * HTS + rg * 2];
            const float* wrow = &Ws[(kc * 16 + kk) * FEAT + c0];
            float4 w0 = ((const float4*)wrow)[0];
            float4 w1 = ((const float4*)wrow)[1];
            float4 w2 = ((const float4*)wrow)[2];
            float4 w3 = ((const float4*)wrow)[3];
            const float w[16] = {w0.x, w0.y, w0.z, w0.w, w1.x, w1.y, w1.z, w1.w,
                                 w2.x, w2.y, w2.z, w2.w, w3.x, w3.y, w3.z, w3.w};
#pragma unroll
            for (int j = 0; j < 16; ++j) {
                acc[0][j] = fmaf(a2.x, w[j], acc[0][j]);
                acc[1][j] = fmaf(a2.y, w[j], acc[1][j]);
            }
        }
    }

#pragma unroll
    for (int i = 0; i < 2; ++i) {
        int r = r0 + rg * 2 + i;
        if (r >= N_NODES) continue;
        float nr = rsqrtf(fmaxf((float)deg[r], 1.f));
        float xa = 0.f, xb = 0.f;
        alignas(16) __half hv[16];
        float vs[16];
#pragma unroll
        for (int j = 0; j < 16; ++j) {
            float v = acc[i][j] + b1[c0 + j];
            v = v > 0.f ? v : 0.f;
            xa = fmaf(v, gate_W[32 + j], xa);   // dst-side gate (raw x)
            xb = fmaf(v, gate_W[48 + j], xb);   // src-side gate
            float sv = v * nr;
            vs[j] = sv;
            hv[j] = __float2half(sv);
        }
        // fp16 row (residual path)
        float4* xp = (float4*)(xs2h + (size_t)r * FEAT + c0);
        xp[0] = *(const float4*)&hv[0];
        xp[1] = *(const float4*)&hv[8];
        // fp8 row (gather path): 4 uints = 16 bytes
        unsigned int u[4];
#pragma unroll
        for (int q = 0; q < 4; ++q) {
            unsigned int t = 0;
            t = __builtin_amdgcn_cvt_pk_fp8_f32(vs[q*4+0], vs[q*4+1], t, false);
            t = __builtin_amdgcn_cvt_pk_fp8_f32(vs[q*4+2], vs[q*4+3], t, true);
            u[q] = t;
        }
        ((uint4*)xq)[(size_t)r * 4 + cg] = make_uint4(u[0], u[1], u[2], u[3]);
        aproj[(size_t)r * 4 + cg] = xa;
        bproj[(size_t)r * 4 + cg] = xb;
    }
}

// ---------------- aggregate: 16 edges/wave (4 lanes/edge), fp8 gather, fp16 residual ----------------
// lane = e*4 + l4 : e = edge slot 0..15, l4 = head 0..3, lane owns feats [l4*16, l4*16+16)
// (round-2 proven version: VGPR 28, Occ ~68%, 49.5 us)
__global__ __launch_bounds__(256) void k_aggregate(
    const uint4* __restrict__ xq4, const __half2* __restrict__ xs2h2,
    const float* __restrict__ aproj, const float* __restrict__ bproj,
    const int* __restrict__ rowptr, const int* __restrict__ src_sorted,
    const float* __restrict__ gate_b, float* __restrict__ v_out)
{
    const int tid    = threadIdx.x;
    const int lane   = tid & 63;
    const int e      = lane >> 2;        // edge slot within the 16-edge group
    const int l4     = lane & 3;         // head
    const int wave   = blockIdx.x * 4 + (tid >> 6);
    const int nwaves = gridDim.x * 4;
    const float gb   = gate_b[1];
    const float C    = 2.8853900817779268f;   // 2*log2(e): tanh(p)=1-2/(exp2(C*p)+1)

    for (int n = wave; n < N_NODES; n += nwaves) {
        const int beg = rowptr[n];
        const int end = rowptr[n + 1];
        const int cnt = end - beg;
        const float a_d = aproj[(size_t)n * 4 + l4] + gb;

        float acc[16];
#pragma unroll
        for (int k = 0; k < 16; ++k) acc[k] = 0.f;

        if (cnt > 0) {
            const int last = end - 1;
            // prefetch: src 2 groups ahead, xq/bproj 1 group ahead
            int  j0  = beg + e;
            bool ok0 = j0 < end;
            int  s0  = src_sorted[ok0 ? j0 : last];
            uint4 x0 = xq4[(size_t)s0 * 4 + l4];
            float b0 = bproj[(size_t)s0 * 4 + l4];
            int  j1  = j0 + 16;
            bool ok1 = j1 < end;
            int  s1  = src_sorted[ok1 ? j1 : last];

            for (int j = beg; j < end; j += 16) {
                const bool more = (j + 16) < end;   // wave-uniform
                uint4 x1 = make_uint4(0u, 0u, 0u, 0u);
                float b1 = 0.f;
                int   s2 = s1;
                bool  ok2 = false;
                if (more) {
                    x1 = xq4[(size_t)s1 * 4 + l4];
                    b1 = bproj[(size_t)s1 * 4 + l4];
                    int j2 = j + 32 + e;
                    ok2 = j2 < end;
                    s2 = src_sorted[ok2 ? j2 : last];
                }
                // gate: one tanh per (edge, head)
                float ex = __builtin_amdgcn_exp2f(C * (a_d + b0));
                float t  = 1.f - 2.f * __builtin_amdgcn_rcpf(ex + 1.f);
                t = ok0 ? t : 0.f;
                // decode 16 fp8 feats (one head's row-quarter) + fma
#pragma unroll
                for (int w = 0; w < 4; ++w) {
                    const unsigned int xw = ((const unsigned int*)&x0)[w];
                    vfloat2 lo = __builtin_amdgcn_cvt_pk_f32_fp8(xw, false);
                    vfloat2 hi = __builtin_amdgcn_cvt_pk_f32_fp8(xw, true);
                    acc[w * 4 + 0] = fmaf(t, lo[0], acc[w * 4 + 0]);
                    acc[w * 4 + 1] = fmaf(t, lo[1], acc[w * 4 + 1]);
                    acc[w * 4 + 2] = fmaf(t, hi[0], acc[w * 4 + 2]);
                    acc[w * 4 + 3] = fmaf(t, hi[1], acc[w * 4 + 3]);
                }
                if (more) {
                    x0 = x1; b0 = b1; ok0 = ok1; ok1 = ok2; s1 = s2;
                }
            }
        }

        // ---- fold-reduce across the 16 edge slots (lanes stride 4) ----
        const bool elo = (e & 1) == 0;
        float r8[8];
#pragma unroll
        for (int i = 0; i < 8; ++i) {
            float give = elo ? acc[8 + i] : acc[i];
            float got  = __shfl_xor(give, 4, 64);
            r8[i] = (elo ? acc[i] : acc[8 + i]) + got;
        }
        const bool e2lo = (e & 2) == 0;
        float v4[4];
#pragma unroll
        for (int i = 0; i < 4; ++i) {
            float give = e2lo ? r8[4 + i] : r8[i];
            float got  = __shfl_xor(give, 8, 64);
            v4[i] = (e2lo ? r8[i] : r8[4 + i]) + got;
        }
#pragma unroll
        for (int i = 0; i < 4; ++i) v4[i] += __shfl_xor(v4[i], 16, 64);
#pragma unroll
        for (int i = 0; i < 4; ++i) v4[i] += __shfl_xor(v4[i], 32, 64);
        // lane (e,l4) holds feat-quad q(e) = (e&1)*2 | ((e>>1)&1) of head l4

        const float dg = fmaxf((float)cnt, 1.f);
        const float nd = rsqrtf(dg);      // norm[n]
        const float sd = dg * nd;         // sqrt(deg) = 1/norm

        if (e < 4) {
            const int q = ((e & 1) << 1) | ((e >> 1) & 1);
            const int Q = l4 * 4 + q;     // flat feat-quad 0..15
            const __half2* hp = xs2h2 + (size_t)n * 32 + Q * 2;
            float2 fa = __half22float2(hp[0]);
            float2 fb = __half22float2(hp[1]);
            float4 v;
            v.x = fmaf(0.5f * sd, fa.x, v4[0] * nd);
            v.y = fmaf(0.5f * sd, fa.y, v4[1] * nd);
            v.z = fmaf(0.5f * sd, fb.x, v4[2] * nd);
            v.w = fmaf(0.5f * sd, fb.y, v4[3] * nd);
            ((float4*)v_out)[(size_t)n * 16 + Q] = v;
        }
    }
}

// ---------------- gemm2: W2-in-registers matvec, in-place on d_out ----------------
// lane = kc*16 + oq : kc = k-chunk (16 k each), oq = out quad. W2 slice [16][4] in 16 float4 regs,
// reused across all nodes. Per node: 64 fma (4 indep chains) + 2 shfl_xor reduce + 1 float4 store.
__global__ __launch_bounds__(256) void k_gemm2(
    float* __restrict__ v, const float* __restrict__ W2, const float* __restrict__ b2)
{
    const int tid    = threadIdx.x;
    const int lane   = tid & 63;
    const int kc     = lane >> 4;        // 0..3
    const int oq     = lane & 15;        // 0..15
    const int wave   = blockIdx.x * 4 + (tid >> 6);
    const int nwaves = gridDim.x * 4;

    // W2 slice: rows kc*16..+16, cols oq*4..+4  (L2-cached, read once per lane)
    float4 wreg[16];
#pragma unroll
    for (int j = 0; j < 16; ++j)
        wreg[j] = *(const float4*)(W2 + (size_t)(kc * 16 + j) * OUT_DIM + oq * 4);
    const float4 bq = ((const float4*)b2)[oq];

    for (int n = wave; n < N_NODES; n += nwaves) {
        const float4* vrow = (const float4*)(v + (size_t)n * FEAT) + kc * 4;
        float4 q0 = vrow[0], q1 = vrow[1], q2 = vrow[2], q3 = vrow[3];
        const float vs[16] = {q0.x, q0.y, q0.z, q0.w, q1.x, q1.y, q1.z, q1.w,
                              q2.x, q2.y, q2.z, q2.w, q3.x, q3.y, q3.z, q3.w};
        float ax = 0.f, ay = 0.f, az = 0.f, aw = 0.f;
#pragma unroll
        for (int j = 0; j < 16; ++j) {
            ax = fmaf(vs[j], wreg[j].x, ax);
            ay = fmaf(vs[j], wreg[j].y, ay);
            az = fmaf(vs[j], wreg[j].z, az);
            aw = fmaf(vs[j], wreg[j].w, aw);
        }
        // reduce over kc (lane bits 4,5)
        ax += __shfl_xor(ax, 16, 64); ay += __shfl_xor(ay, 16, 64);
        az += __shfl_xor(az, 16, 64); aw += __shfl_xor(aw, 16, 64);
        ax += __shfl_xor(ax, 32, 64); ay += __shfl_xor(ay, 32, 64);
        az += __shfl_xor(az, 32, 64); aw += __shfl_xor(aw, 32, 64);
        if (kc == 0) {
            float4 o = make_float4(ax + bq.x, ay + bq.y, az + bq.z, aw + bq.w);
            // all reads of row n (by this wave only) precede this store in wave-lockstep order
            ((float4*)v)[(size_t)n * 16 + oq] = o;
        }
    }
}

extern "C" void kernel_launch(void* const* d_in, const int* in_sizes, int n_in,
                              void* d_out, int out_size, void* d_ws, size_t ws_size,
                              hipStream_t stream)
{
    const float* h   = (const float*)d_in[0];
    const int*   src = (const int*)d_in[1];
    const int*   dst = (const int*)d_in[2];
    const float* W1  = (const float*)d_in[3];
    const float* b1  = (const float*)d_in[4];
    const float* W2  = (const float*)d_in[5];
    const float* b2  = (const float*)d_in[6];
    const float* gW  = (const float*)d_in[7];
    const float* gb  = (const float*)d_in[8];
    float* out = (float*)d_out;

    // ws: bucket_cursor[NBKT] | binned[NBKT*CAP] | src_sorted[E] | rowptr[N+1] | deg[N]
    //     | aproj[N*4] | bproj[N*4] | xs2h[N*64] f16 | xq[N*16] u32 (fp8)
    int* bucket_cursor = (int*)d_ws;
    int* binned        = bucket_cursor + NBKT;
    int* src_sorted    = binned + (size_t)NBKT * CAP;
    int* rowptr        = src_sorted + E_EDGES;
    int* deg           = rowptr + (N_NODES + 1);
    float* aproj       = (float*)(deg + N_NODES);
    float* bproj       = aproj + (size_t)N_NODES * 4;
    __half* xs2h       = (__half*)(bproj + (size_t)N_NODES * 4);
    unsigned int* xq   = (unsigned int*)(xs2h + (size_t)N_NODES * FEAT);

    hipMemsetAsync(bucket_cursor, 0, NBKT * sizeof(int), stream);

    k_binscatter <<<NSCB, 256, 0, stream>>>(src, dst, bucket_cursor, binned);
    k_bucketfinal<<<NBKT, 256, 0, stream>>>(binned, bucket_cursor, deg, rowptr, src_sorted);
    k_gemm1      <<<G1B2, 256, 0, stream>>>(h, W1, b1, deg, gW, xs2h, xq, aproj, bproj);
    k_aggregate  <<<2048, 256, 0, stream>>>((const uint4*)xq, (const __half2*)xs2h,
                                            aproj, bproj, rowptr, src_sorted, gb, out);
    k_gemm2      <<<1024, 256, 0, stream>>>(out, W2, b2);
}

// Round 10
// 244.121 us; speedup vs baseline: 1.0628x; 1.0628x over previous
//
#include <hip/hip_runtime.h>
#include <hip/hip_fp16.h>
#include <math.h>

#define N_NODES 100000
#define E_EDGES 1600000
#define IN_DIM  128
#define FEAT    64
#define OUT_DIM 64
#define NBKT    391            // ceil(100000/256) buckets of 256 nodes (dst>>8)
#define CAP     6144           // per-bucket capacity (avg 4096, >30 sigma slack)
#define RNG     4096           // edges per binscatter block
#define NSCB    ((E_EDGES + RNG - 1) / RNG)   // 391
#define G1B     ((N_NODES + 255) / 256)       // 391

typedef float vfloat2 __attribute__((ext_vector_type(2)));

// ---------------- binscatter: block-local counting sort into 391 dst-buckets ----------------
__global__ __launch_bounds__(256) void k_binscatter(
    const int* __restrict__ src, const int* __restrict__ dst,
    int* __restrict__ bucket_cursor, int* __restrict__ binned)
{
    __shared__ int hist[NBKT];
    __shared__ int baseS[NBKT];
    __shared__ int cursor[NBKT];
    __shared__ int gbase[NBKT];          // after reserve: gbase[b] - baseS[b]
    __shared__ int sA[512], sB[512];
    __shared__ int buf[RNG];             // 16 KB
    __shared__ unsigned short bkt[RNG];  // 8 KB

    const int tid  = threadIdx.x;
    const int e0   = blockIdx.x * RNG;
    const int ecnt = min(RNG, E_EDGES - e0);

    for (int i = tid; i < NBKT; i += 256) hist[i] = 0;
    __syncthreads();

    int dsave[16];
#pragma unroll
    for (int k = 0; k < 16; ++k) {
        int e = e0 + k * 256 + tid;
        int d = (e < E_EDGES) ? dst[e] : -1;
        dsave[k] = d;
        if (d >= 0) atomicAdd(&hist[d >> 8], 1);
    }
    __syncthreads();

    for (int i = tid; i < 512; i += 256) sA[i] = (i < NBKT) ? hist[i] : 0;
    __syncthreads();
    int* pa = sA; int* pb = sB;
    for (int off = 1; off < 512; off <<= 1) {
        for (int i = tid; i < 512; i += 256)
            pb[i] = pa[i] + ((i >= off) ? pa[i - off] : 0);
        __syncthreads();
        int* t = pa; pa = pb; pb = t;
    }
    for (int i = tid; i < NBKT; i += 256) {
        int ex = pa[i] - hist[i];
        baseS[i]  = ex;
        cursor[i] = ex;
    }
    __syncthreads();

#pragma unroll
    for (int k = 0; k < 16; ++k) {
        int d = dsave[k];
        if (d >= 0) {
            int e   = e0 + k * 256 + tid;
            int s   = src[e];
            int b   = d >> 8;
            int pos = atomicAdd(&cursor[b], 1);
            buf[pos] = ((d & 255) << 17) | s;   // dl:8b | src:17b
            bkt[pos] = (unsigned short)b;
        }
    }
    __syncthreads();

    for (int t = tid; t < NBKT; t += 256) {
        int cnt = hist[t];
        int g   = cnt ? atomicAdd(&bucket_cursor[t], cnt) : 0;
        gbase[t] = g - baseS[t];
    }
    __syncthreads();

    for (int i = tid; i < ecnt; i += 256) {
        int b   = bkt[i];
        int off = gbase[b] + i;
        if (off < CAP) binned[b * CAP + off] = buf[i];
    }
}

// ---------------- bucketfinal: inline scan + per-bucket node sort ----------------
__global__ __launch_bounds__(256) void k_bucketfinal(
    const int* __restrict__ binned, const int* __restrict__ bucket_cursor,
    int* __restrict__ deg, int* __restrict__ rowptr, int* __restrict__ src_sorted)
{
    __shared__ int sA[512], sB[512];
    __shared__ int hist[256];
    __shared__ int scn[256];
    __shared__ int cur[256];
    const int b   = blockIdx.x;
    const int tid = threadIdx.x;

    for (int i = tid; i < 512; i += 256) sA[i] = (i < NBKT) ? bucket_cursor[i] : 0;
    __syncthreads();
    int* pa = sA; int* pb = sB;
    for (int off = 1; off < 512; off <<= 1) {
        for (int i = tid; i < 512; i += 256)
            pb[i] = pa[i] + ((i >= off) ? pa[i - off] : 0);
        __syncthreads();
        int* t = pa; pa = pb; pb = t;
    }
    const int cnt  = bucket_cursor[b];
    const int eb   = pa[b] - cnt;
    const int base = b * CAP;
    __syncthreads();

    hist[tid] = 0;
    __syncthreads();
    for (int i = tid; i < cnt; i += 256)
        atomicAdd(&hist[binned[base + i] >> 17], 1);
    __syncthreads();

    int v = hist[tid];
    scn[tid] = v;
    __syncthreads();
    for (int off = 1; off < 256; off <<= 1) {
        int add = (tid >= off) ? scn[tid - off] : 0;
        __syncthreads();
        scn[tid] += add;
        __syncthreads();
    }
    int ex = scn[tid] - v;
    cur[tid] = ex;
    int n = b * 256 + tid;
    if (n < N_NODES) {
        deg[n]    = v;
        rowptr[n] = eb + ex;
    }
    if (b == 0 && tid == 0) rowptr[N_NODES] = E_EDGES;
    __syncthreads();

    for (int i = tid; i < cnt; i += 256) {
        int p   = binned[base + i];
        int dl  = p >> 17;
        int pos = atomicAdd(&cur[dl], 1);
        src_sorted[eb + pos] = p & 0x1FFFF;
    }
}

// ---------------- gemm1: 256-row blocks + register prefetch of next h-chunk ----------------
__global__ __launch_bounds__(256) void k_gemm1(
    const float* __restrict__ h, const float* __restrict__ W1,
    const float* __restrict__ b1, const int* __restrict__ deg,
    const float* __restrict__ gate_W,
    __half* __restrict__ xs2h, unsigned int* __restrict__ xq,
    float* __restrict__ aproj, float* __restrict__ bproj)
{
    __shared__ float Ws[IN_DIM * FEAT];   // 32 KB
    __shared__ float hT[16 * 260];        // 16.25 KB transposed tile
    const int tid = threadIdx.x;
    const int r0  = blockIdx.x * 256;

    for (int i = tid; i < IN_DIM * FEAT / 4; i += 256)
        ((float4*)Ws)[i] = ((const float4*)W1)[i];

    const int rg = tid >> 2;     // 0..63: row group (4 rows)
    const int cg = tid & 3;      // 0..3: col group == head
    const int c0 = cg * 16;
    float acc[4][16];
#pragma unroll
    for (int i = 0; i < 4; ++i)
#pragma unroll
        for (int j = 0; j < 16; ++j) acc[i][j] = 0.f;

    const int  myrow = r0 + tid;
    const bool rok   = myrow < N_NODES;
    const float4* hp = (const float4*)(h + (size_t)myrow * IN_DIM);

    // preload chunk 0 (OOB rows stay zero forever: loads are guarded, f never overwritten)
    float4 f[4];
    if (rok) { f[0] = hp[0]; f[1] = hp[1]; f[2] = hp[2]; f[3] = hp[3]; }
    else     { f[0] = f[1] = f[2] = f[3] = make_float4(0.f, 0.f, 0.f, 0.f); }

    for (int kc = 0; kc < IN_DIM / 16; ++kc) {
        __syncthreads();
#pragma unroll
        for (int q = 0; q < 4; ++q) {
            hT[(q * 4 + 0) * 260 + tid] = f[q].x;
            hT[(q * 4 + 1) * 260 + tid] = f[q].y;
            hT[(q * 4 + 2) * 260 + tid] = f[q].z;
            hT[(q * 4 + 3) * 260 + tid] = f[q].w;
        }
        __syncthreads();
        // prefetch NEXT chunk now — latency hides under this chunk's 16x64 FMA phase;
        // vmcnt wait lands at next iteration's hT writes (after the barrier).
        if (kc + 1 < IN_DIM / 16 && rok) {
            f[0] = hp[(kc + 1) * 4 + 0];
            f[1] = hp[(kc + 1) * 4 + 1];
            f[2] = hp[(kc + 1) * 4 + 2];
            f[3] = hp[(kc + 1) * 4 + 3];
        }
#pragma unroll
        for (int kk = 0; kk < 16; ++kk) {
            float4 a4 = *(const float4*)&hT[kk * 260 + rg * 4];
            const float* wrow = &Ws[(kc * 16 + kk) * FEAT + c0];
            float4 w0 = ((const float4*)wrow)[0];
            float4 w1 = ((const float4*)wrow)[1];
            float4 w2 = ((const float4*)wrow)[2];
            float4 w3 = ((const float4*)wrow)[3];
            const float a[4] = {a4.x, a4.y, a4.z, a4.w};
            const float w[16] = {w0.x, w0.y, w0.z, w0.w, w1.x, w1.y, w1.z, w1.w,
                                 w2.x, w2.y, w2.z, w2.w, w3.x, w3.y, w3.z, w3.w};
#pragma unroll
            for (int i = 0; i < 4; ++i)
#pragma unroll
                for (int j = 0; j < 16; ++j)
                    acc[i][j] = fmaf(a[i], w[j], acc[i][j]);
        }
    }

#pragma unroll
    for (int i = 0; i < 4; ++i) {
        int r = r0 + rg * 4 + i;
        if (r >= N_NODES) continue;
        float nr = rsqrtf(fmaxf((float)deg[r], 1.f));
        float xa = 0.f, xb = 0.f;
        alignas(16) __half hv[16];
        float vs[16];
#pragma unroll
        for (int j = 0; j < 16; ++j) {
            float v = acc[i][j] + b1[c0 + j];
            v = v > 0.f ? v : 0.f;
            xa = fmaf(v, gate_W[32 + j], xa);   // dst-side gate (raw x)
            xb = fmaf(v, gate_W[48 + j], xb);   // src-side gate
            float sv = v * nr;
            vs[j] = sv;
            hv[j] = __float2half(sv);
        }
        // fp16 row (residual path)
        float4* xp = (float4*)(xs2h + (size_t)r * FEAT + c0);
        xp[0] = *(const float4*)&hv[0];
        xp[1] = *(const float4*)&hv[8];
        // fp8 row (gather path): 4 uints = 16 bytes
        unsigned int u[4];
#pragma unroll
        for (int q = 0; q < 4; ++q) {
            unsigned int t = 0;
            t = __builtin_amdgcn_cvt_pk_fp8_f32(vs[q*4+0], vs[q*4+1], t, false);
            t = __builtin_amdgcn_cvt_pk_fp8_f32(vs[q*4+2], vs[q*4+3], t, true);
            u[q] = t;
        }
        ((uint4*)xq)[(size_t)r * 4 + cg] = make_uint4(u[0], u[1], u[2], u[3]);
        aproj[(size_t)r * 4 + cg] = xa;
        bproj[(size_t)r * 4 + cg] = xb;
    }
}

// ---------------- aggregate: 16 edges/wave (4 lanes/edge), fp8 gather, fp16 residual ----------------
// lane = e*4 + l4 : e = edge slot 0..15, l4 = head 0..3, lane owns feats [l4*16, l4*16+16)
// (round-2 proven version: VGPR 28, Occ ~68%, 49.5 us)
__global__ __launch_bounds__(256) void k_aggregate(
    const uint4* __restrict__ xq4, const __half2* __restrict__ xs2h2,
    const float* __restrict__ aproj, const float* __restrict__ bproj,
    const int* __restrict__ rowptr, const int* __restrict__ src_sorted,
    const float* __restrict__ gate_b, float* __restrict__ v_out)
{
    const int tid    = threadIdx.x;
    const int lane   = tid & 63;
    const int e      = lane >> 2;        // edge slot within the 16-edge group
    const int l4     = lane & 3;         // head
    const int wave   = blockIdx.x * 4 + (tid >> 6);
    const int nwaves = gridDim.x * 4;
    const float gb   = gate_b[1];
    const float C    = 2.8853900817779268f;   // 2*log2(e): tanh(p)=1-2/(exp2(C*p)+1)

    for (int n = wave; n < N_NODES; n += nwaves) {
        const int beg = rowptr[n];
        const int end = rowptr[n + 1];
        const int cnt = end - beg;
        const float a_d = aproj[(size_t)n * 4 + l4] + gb;

        float acc[16];
#pragma unroll
        for (int k = 0; k < 16; ++k) acc[k] = 0.f;

        if (cnt > 0) {
            const int last = end - 1;
            // prefetch: src 2 groups ahead, xq/bproj 1 group ahead
            int  j0  = beg + e;
            bool ok0 = j0 < end;
            int  s0  = src_sorted[ok0 ? j0 : last];
            uint4 x0 = xq4[(size_t)s0 * 4 + l4];
            float b0 = bproj[(size_t)s0 * 4 + l4];
            int  j1  = j0 + 16;
            bool ok1 = j1 < end;
            int  s1  = src_sorted[ok1 ? j1 : last];

            for (int j = beg; j < end; j += 16) {
                const bool more = (j + 16) < end;   // wave-uniform
                uint4 x1 = make_uint4(0u, 0u, 0u, 0u);
                float b1 = 0.f;
                int   s2 = s1;
                bool  ok2 = false;
                if (more) {
                    x1 = xq4[(size_t)s1 * 4 + l4];
                    b1 = bproj[(size_t)s1 * 4 + l4];
                    int j2 = j + 32 + e;
                    ok2 = j2 < end;
                    s2 = src_sorted[ok2 ? j2 : last];
                }
                // gate: one tanh per (edge, head)
                float ex = __builtin_amdgcn_exp2f(C * (a_d + b0));
                float t  = 1.f - 2.f * __builtin_amdgcn_rcpf(ex + 1.f);
                t = ok0 ? t : 0.f;
                // decode 16 fp8 feats (one head's row-quarter) + fma
#pragma unroll
                for (int w = 0; w < 4; ++w) {
                    const unsigned int xw = ((const unsigned int*)&x0)[w];
                    vfloat2 lo = __builtin_amdgcn_cvt_pk_f32_fp8(xw, false);
                    vfloat2 hi = __builtin_amdgcn_cvt_pk_f32_fp8(xw, true);
                    acc[w * 4 + 0] = fmaf(t, lo[0], acc[w * 4 + 0]);
                    acc[w * 4 + 1] = fmaf(t, lo[1], acc[w * 4 + 1]);
                    acc[w * 4 + 2] = fmaf(t, hi[0], acc[w * 4 + 2]);
                    acc[w * 4 + 3] = fmaf(t, hi[1], acc[w * 4 + 3]);
                }
                if (more) {
                    x0 = x1; b0 = b1; ok0 = ok1; ok1 = ok2; s1 = s2;
                }
            }
        }

        // ---- fold-reduce across the 16 edge slots (lanes stride 4) ----
        const bool elo = (e & 1) == 0;
        float r8[8];
#pragma unroll
        for (int i = 0; i < 8; ++i) {
            float give = elo ? acc[8 + i] : acc[i];
            float got  = __shfl_xor(give, 4, 64);
            r8[i] = (elo ? acc[i] : acc[8 + i]) + got;
        }
        const bool e2lo = (e & 2) == 0;
        float v4[4];
#pragma unroll
        for (int i = 0; i < 4; ++i) {
            float give = e2lo ? r8[4 + i] : r8[i];
            float got  = __shfl_xor(give, 8, 64);
            v4[i] = (e2lo ? r8[i] : r8[4 + i]) + got;
        }
#pragma unroll
        for (int i = 0; i < 4; ++i) v4[i] += __shfl_xor(v4[i], 16, 64);
#pragma unroll
        for (int i = 0; i < 4; ++i) v4[i] += __shfl_xor(v4[i], 32, 64);
        // lane (e,l4) holds feat-quad q(e) = (e&1)*2 | ((e>>1)&1) of head l4

        const float dg = fmaxf((float)cnt, 1.f);
        const float nd = rsqrtf(dg);      // norm[n]
        const float sd = dg * nd;         // sqrt(deg) = 1/norm

        if (e < 4) {
            const int q = ((e & 1) << 1) | ((e >> 1) & 1);
            const int Q = l4 * 4 + q;     // flat feat-quad 0..15
            const __half2* hp = xs2h2 + (size_t)n * 32 + Q * 2;
            float2 fa = __half22float2(hp[0]);
            float2 fb = __half22float2(hp[1]);
            float4 v;
            v.x = fmaf(0.5f * sd, fa.x, v4[0] * nd);
            v.y = fmaf(0.5f * sd, fa.y, v4[1] * nd);
            v.z = fmaf(0.5f * sd, fb.x, v4[2] * nd);
            v.w = fmaf(0.5f * sd, fb.y, v4[3] * nd);
            ((float4*)v_out)[(size_t)n * 16 + Q] = v;
        }
    }
}

// ---------------- gemm2: W2-in-registers matvec, in-place on d_out ----------------
// lane = kc*16 + oq : kc = k-chunk (16 k each), oq = out quad. W2 slice [16][4] in 16 float4 regs,
// reused across all nodes. Per node: 64 fma (4 indep chains) + 2 shfl_xor reduce + 1 float4 store.
__global__ __launch_bounds__(256) void k_gemm2(
    float* __restrict__ v, const float* __restrict__ W2, const float* __restrict__ b2)
{
    const int tid    = threadIdx.x;
    const int lane   = tid & 63;
    const int kc     = lane >> 4;        // 0..3
    const int oq     = lane & 15;        // 0..15
    const int wave   = blockIdx.x * 4 + (tid >> 6);
    const int nwaves = gridDim.x * 4;

    // W2 slice: rows kc*16..+16, cols oq*4..+4  (L2-cached, read once per lane)
    float4 wreg[16];
#pragma unroll
    for (int j = 0; j < 16; ++j)
        wreg[j] = *(const float4*)(W2 + (size_t)(kc * 16 + j) * OUT_DIM + oq * 4);
    const float4 bq = ((const float4*)b2)[oq];

    for (int n = wave; n < N_NODES; n += nwaves) {
        const float4* vrow = (const float4*)(v + (size_t)n * FEAT) + kc * 4;
        float4 q0 = vrow[0], q1 = vrow[1], q2 = vrow[2], q3 = vrow[3];
        const float vs[16] = {q0.x, q0.y, q0.z, q0.w, q1.x, q1.y, q1.z, q1.w,
                              q2.x, q2.y, q2.z, q2.w, q3.x, q3.y, q3.z, q3.w};
        float ax = 0.f, ay = 0.f, az = 0.f, aw = 0.f;
#pragma unroll
        for (int j = 0; j < 16; ++j) {
            ax = fmaf(vs[j], wreg[j].x, ax);
            ay = fmaf(vs[j], wreg[j].y, ay);
            az = fmaf(vs[j], wreg[j].z, az);
            aw = fmaf(vs[j], wreg[j].w, aw);
        }
        // reduce over kc (lane bits 4,5)
        ax += __shfl_xor(ax, 16, 64); ay += __shfl_xor(ay, 16, 64);
        az += __shfl_xor(az, 16, 64); aw += __shfl_xor(aw, 16, 64);
        ax += __shfl_xor(ax, 32, 64); ay += __shfl_xor(ay, 32, 64);
        az += __shfl_xor(az, 32, 64); aw += __shfl_xor(aw, 32, 64);
        if (kc == 0) {
            float4 o = make_float4(ax + bq.x, ay + bq.y, az + bq.z, aw + bq.w);
            // all reads of row n (by this wave only) precede this store in wave-lockstep order
            ((float4*)v)[(size_t)n * 16 + oq] = o;
        }
    }
}

extern "C" void kernel_launch(void* const* d_in, const int* in_sizes, int n_in,
                              void* d_out, int out_size, void* d_ws, size_t ws_size,
                              hipStream_t stream)
{
    const float* h   = (const float*)d_in[0];
    const int*   src = (const int*)d_in[1];
    const int*   dst = (const int*)d_in[2];
    const float* W1  = (const float*)d_in[3];
    const float* b1  = (const float*)d_in[4];
    const float* W2  = (const float*)d_in[5];
    const float* b2  = (const float*)d_in[6];
    const float* gW  = (const float*)d_in[7];
    const float* gb  = (const float*)d_in[8];
    float* out = (float*)d_out;

    // ws: bucket_cursor[NBKT] | binned[NBKT*CAP] | src_sorted[E] | rowptr[N+1] | deg[N]
    //     | aproj[N*4] | bproj[N*4] | xs2h[N*64] f16 | xq[N*16] u32 (fp8)
    int* bucket_cursor = (int*)d_ws;
    int* binned        = bucket_cursor + NBKT;
    int* src_sorted    = binned + (size_t)NBKT * CAP;
    int* rowptr        = src_sorted + E_EDGES;
    int* deg           = rowptr + (N_NODES + 1);
    float* aproj       = (float*)(deg + N_NODES);
    float* bproj       = aproj + (size_t)N_NODES * 4;
    __half* xs2h       = (__half*)(bproj + (size_t)N_NODES * 4);
    unsigned int* xq   = (unsigned int*)(xs2h + (size_t)N_NODES * FEAT);

    hipMemsetAsync(bucket_cursor, 0, NBKT * sizeof(int), stream);

    k_binscatter <<<NSCB, 256, 0, stream>>>(src, dst, bucket_cursor, binned);
    k_bucketfinal<<<NBKT, 256, 0, stream>>>(binned, bucket_cursor, deg, rowptr, src_sorted);
    k_gemm1      <<<G1B, 256, 0, stream>>>(h, W1, b1, deg, gW, xs2h, xq, aproj, bproj);
    k_aggregate  <<<2048, 256, 0, stream>>>((const uint4*)xq, (const __half2*)xs2h,
                                            aproj, bproj, rowptr, src_sorted, gb, out);
    k_gemm2      <<<1024, 256, 0, stream>>>(out, W2, b2);
}